// Round 12
// baseline (415.642 us; speedup 1.0000x reference)
//
#include <hip/hip_runtime.h>
#include <hip/hip_bf16.h>

#define DEV __device__ __forceinline__

typedef __bf16 bf16x8 __attribute__((ext_vector_type(8)));
typedef float f32x4 __attribute__((ext_vector_type(4)));

DEV f32x4 mfma16(bf16x8 a, bf16x8 b, f32x4 c) {
  return __builtin_amdgcn_mfma_f32_16x16x32_bf16(a, b, c, 0, 0, 0);
}

DEV ushort f2bf(float f) {
  union { __hip_bfloat16 h; ushort u; } cv;
  cv.h = __float2bfloat16(f);
  return cv.u;
}
DEV float bf2f(ushort u) {
  union { float f; unsigned v; } cv; cv.v = ((unsigned)u) << 16; return cv.f;
}

// ---------------- constants ----------------
// B=4 H=8 S=2048 D=256; BH=32; M=B*S=8192
// K global layout: [bh][t][256] bf16, pre-swizzled: chunk(e>>3) ^= (t&7)  (T2 swizzle)
// V global layout: [bh][ttile=t/32][256 e][32 t] bf16 tiles (16KB), scaled by 1/l_t (vscale)
// lp: [64 partials (stile*4+w)][32 bh][2048 t] fp32  (16 stiles x 4 waves)
// NOTE: K staging reg-staged, NOT global_load_lds (r3 corruption).
// r11 lesson: p0 s-tile-128 at (256,4) hit the 128-VGPR wall -> allocator spilled q
//   (VGPR_Count 60, WRITE 267MB, 169us). Demand ~115 vs cap 128: too tight.
// r12: p0 launch_bounds (256,4) -> (256,3): cap ~170, expected alloc ~115-128,
//   HW still fits 4 blocks/CU if alloc <= 128. Single-variable change.

// ---------------- kernel A: fp32 -> bf16 conversion ----------------
__global__ __launch_bounds__(256) void convert_all(
    const float* __restrict__ x, const float* __restrict__ wq,
    const float* __restrict__ wk, const float* __restrict__ wv,
    const float* __restrict__ wo, ushort* __restrict__ dst)
{
  size_t i = ((size_t)blockIdx.x * 256 + threadIdx.x) * 4;
  const float* src; size_t off;
  if (i < (size_t)2097152) { src = x; off = i; }
  else {
    size_t j = i - 2097152;
    unsigned wsel = (unsigned)(j >> 19);
    off = j & 524287;
    src = wsel == 0 ? wq : wsel == 1 ? wk : wsel == 2 ? wv : wo;
  }
  float4 v = *(const float4*)(src + off);
  ushort4 o;
  o.x = f2bf(v.x); o.y = f2bf(v.y); o.z = f2bf(v.z); o.w = f2bf(v.w);
  *(ushort4*)(dst + i) = o;
}

// ---------------- GEMM template (NT: A[M,K] row-major, Bt[N,K] row-major) ----------------
template<int BM, int BN, int EPI>
__global__ __launch_bounds__(256, 2) void gemm_nt(
    const ushort* __restrict__ A,
    const ushort* __restrict__ W0, const ushort* __restrict__ W1, const ushort* __restrict__ W2,
    int K,
    const float* __restrict__ b0, const float* __restrict__ b1, const float* __restrict__ b2,
    ushort* __restrict__ Qo, ushort* __restrict__ Ko, ushort* __restrict__ Vo,
    float* __restrict__ fo)
{
  constexpr int WM = BM / 2, WN = BN / 2, MF = WM / 16, NF = WN / 16;
  constexpr int CA = BM / 64, CB = BN / 64;
  const int n0 = blockIdx.x * BN, m0 = blockIdx.y * BM;
  const int tid = threadIdx.x, lane = tid & 63;
  const int wm = (tid >> 7) & 1, wn = (tid >> 6) & 1;

  __shared__ ushort As[BM * 40];
  __shared__ ushort Bs[BN * 40];

  const ushort* Bt;
  if (EPI == 0) {
    int p = n0 >> 11;
    Bt = (p == 0 ? W0 : p == 1 ? W1 : W2) + (size_t)(n0 & 2047) * K;
  } else {
    Bt = W0 + (size_t)n0 * K;
  }

  f32x4 acc[MF][NF];
#pragma unroll
  for (int m = 0; m < MF; m++)
#pragma unroll
    for (int n = 0; n < NF; n++) acc[m][n] = (f32x4){0.f, 0.f, 0.f, 0.f};

  for (int k0 = 0; k0 < K; k0 += 32) {
#pragma unroll
    for (int i = 0; i < CA; i++) {
      int ci = tid * CA + i; int r = ci >> 2, c = ci & 3;
      *(uint4*)&As[r * 40 + c * 8] = *(const uint4*)&A[(size_t)(m0 + r) * K + k0 + c * 8];
    }
#pragma unroll
    for (int i = 0; i < CB; i++) {
      int ci = tid * CB + i; int r = ci >> 2, c = ci & 3;
      *(uint4*)&Bs[r * 40 + c * 8] = *(const uint4*)&Bt[(size_t)r * K + k0 + c * 8];
    }
    __syncthreads();
    bf16x8 af[MF], bfr[NF];
#pragma unroll
    for (int m = 0; m < MF; m++)
      af[m] = *(const bf16x8*)&As[(wm * WM + m * 16 + (lane & 15)) * 40 + ((lane >> 4) << 3)];
#pragma unroll
    for (int n = 0; n < NF; n++)
      bfr[n] = *(const bf16x8*)&Bs[(wn * WN + n * 16 + (lane & 15)) * 40 + ((lane >> 4) << 3)];
#pragma unroll
    for (int m = 0; m < MF; m++)
#pragma unroll
      for (int n = 0; n < NF; n++) acc[m][n] = mfma16(af[m], bfr[n], acc[m][n]);
    __syncthreads();
  }

  if (EPI == 0) {
    const int p = n0 >> 11;
    const float* bias = (p == 0 ? b0 : p == 1 ? b1 : b2);
    const float scl = (p == 0 ? 0.0625f : 1.0f);
#pragma unroll
    for (int m = 0; m < MF; m++)
#pragma unroll
      for (int n = 0; n < NF; n++)
#pragma unroll
        for (int r = 0; r < 4; r++) {
          int row = m0 + wm * WM + m * 16 + ((lane >> 4) << 2) + r;
          int col = n0 + wn * WN + n * 16 + (lane & 15);
          int ce = col & 2047;
          float v = (acc[m][n][r] + bias[ce]) * scl;
          int b = row >> 11, s = row & 2047, h = ce >> 8, e = ce & 255;
          int bh = b * 8 + h;
          if (p == 0) {
            Qo[((size_t)(bh * 2048 + s) << 8) + e] = f2bf(v);
          } else if (p == 1) {
            int ee = ((((e >> 3) ^ (s & 7)) & 31) << 3) | (e & 7); // T2 pre-swizzle
            Ko[((size_t)(bh * 2048 + s) << 8) + ee] = f2bf(v);
          } else {
            // tiled V': [bh][s>>5][e][s&31]
            Vo[(((size_t)bh * 64 + (s >> 5)) << 13) + e * 32 + (s & 31)] = f2bf(v);
          }
        }
  } else {
#pragma unroll
    for (int m = 0; m < MF; m++)
#pragma unroll
      for (int n = 0; n < NF; n++)
#pragma unroll
        for (int r = 0; r < 4; r++) {
          int row = m0 + wm * WM + m * 16 + ((lane >> 4) << 2) + r;
          int col = n0 + wn * WN + n * 16 + (lane & 15);
          fo[(size_t)row * 256 + col] = acc[m][n][r] + b0[col];
        }
  }
}

// ---------------- attention phase 0: s-tile 128, t-halved, one-barrier pipeline ----------------
// grid 1024 XCD-swizzled; block 256 = 4 waves, each wave 32 s-rows.
// Each block covers t in [half*1024, half*1024+1024) (32 iters of 32 t).
// Column sums of exp(G) -> lp[stile*4+w][bh][t].
// (256,3): VGPR cap ~170 so the ~115-reg body doesn't spill (r11 lesson);
// actual alloc <=128 still lets HW run 4 blocks/CU.
__global__ __launch_bounds__(256, 3) void attn_p0(
    const ushort* __restrict__ Qb, const ushort* __restrict__ Kb,
    float* __restrict__ lpart)
{
  const int bid = blockIdx.x;
  const int swz = (bid & 7) * 128 + (bid >> 3);   // bijective: 1024 % 8 == 0
  const int bh = swz >> 5, stile = (swz >> 1) & 15, half = swz & 1;
  const int s0 = stile * 128;
  const int tid = threadIdx.x, lane = tid & 63, w = tid >> 6;
  const int g = lane >> 4, r15 = lane & 15;

  __shared__ ushort Ks[2][8192];   // dbuf K tile [32 t][256 k], swizzled

  bf16x8 q[2][8];
#pragma unroll
  for (int h = 0; h < 2; ++h) {
    const ushort* qrow = &Qb[((size_t)bh * 2048 + s0 + w * 32 + h * 16 + r15) * 256 + g * 8];
#pragma unroll
    for (int kk = 0; kk < 8; kk++) q[h][kk] = *(const bf16x8*)&qrow[kk * 32];
  }

  const ushort* Ktile = Kb + ((size_t)bh << 19);
  const int it0 = half * 32, it1 = it0 + 32;

  // prologue: stage K(it0)
  uint4 st[4];
#pragma unroll
  for (int i = 0; i < 4; ++i)
    st[i] = *(const uint4*)&Ktile[(size_t)it0 * 8192 + (i * 256 + tid) * 8];
#pragma unroll
  for (int i = 0; i < 4; ++i)
    *(uint4*)&Ks[0][(i * 256 + tid) * 8] = st[i];

  int cur = 0;
  for (int it = it0; it < it1; ++it) {
    __syncthreads();
    if (it < it1 - 1) {
#pragma unroll
      for (int i = 0; i < 4; ++i)
        st[i] = *(const uint4*)&Ktile[(size_t)(it + 1) * 8192 + (i * 256 + tid) * 8];
    }
    // QK^T: 32 s-rows x 32 t per wave; each K-frag read once, used by both halves
    f32x4 gg[2][2];
#pragma unroll
    for (int h = 0; h < 2; ++h)
#pragma unroll
      for (int n = 0; n < 2; ++n) gg[h][n] = (f32x4){0.f, 0.f, 0.f, 0.f};
    const ushort* ks = &Ks[cur][0];
#pragma unroll
    for (int n = 0; n < 2; ++n)
#pragma unroll
      for (int kk = 0; kk < 8; ++kk) {
        bf16x8 kb = *(const bf16x8*)&ks[(n * 16 + r15) * 256 + (((kk * 4 + g) ^ (r15 & 7)) << 3)];
        gg[0][n] = mfma16(q[0][kk], kb, gg[0][n]);
        gg[1][n] = mfma16(q[1][kk], kb, gg[1][n]);
      }
#pragma unroll
    for (int n = 0; n < 2; ++n) {
      float sn = __expf(gg[0][n][0]) + __expf(gg[0][n][1]) + __expf(gg[0][n][2]) + __expf(gg[0][n][3])
               + __expf(gg[1][n][0]) + __expf(gg[1][n][1]) + __expf(gg[1][n][2]) + __expf(gg[1][n][3]);
      sn += __shfl_xor(sn, 16);
      sn += __shfl_xor(sn, 32);
      if (g == 0)
        lpart[((size_t)((stile * 4 + w) * 32 + bh) << 11) + it * 32 + n * 16 + r15] = sn;
    }
    if (it < it1 - 1) {
#pragma unroll
      for (int i = 0; i < 4; ++i)
        *(uint4*)&Ks[cur ^ 1][(i * 256 + tid) * 8] = st[i];
    }
    cur ^= 1;
  }
}

// ---------------- attention phase 1: s-tile 128 + one-barrier pipeline (r10, proven) ----------------
__global__ __launch_bounds__(256, 2) void attn_p1(
    const ushort* __restrict__ Qb, const ushort* __restrict__ Kb,
    const ushort* __restrict__ Vt, ushort* __restrict__ Zb)
{
  const int bid = blockIdx.x;
  const int swz = (bid & 7) * 64 + (bid >> 3);   // bijective: 512 % 8 == 0
  const int bh = swz >> 4, stile = swz & 15;
  const int s0 = stile * 128;
  const int tid = threadIdx.x, lane = tid & 63, w = tid >> 6;
  const int g = lane >> 4, r15 = lane & 15;

  __shared__ __align__(16) ushort Ks[2][8192];   // dbuf K tile [32 t][256 k], swizzled
  __shared__ __align__(16) ushort Ps[2][5120];   // dbuf [128 s][40]

  bf16x8 q[2][8];
#pragma unroll
  for (int h = 0; h < 2; ++h) {
    const ushort* qrow = &Qb[((size_t)bh * 2048 + s0 + w * 32 + h * 16 + r15) * 256 + g * 8];
#pragma unroll
    for (int kk = 0; kk < 8; kk++) q[h][kk] = *(const bf16x8*)&qrow[kk * 32];
  }

  const ushort* Ktile = Kb + ((size_t)bh << 19);
  const ushort* Vtile = Vt + ((size_t)bh << 19);

  f32x4 acc[8][4];
#pragma unroll
  for (int m = 0; m < 8; m++)
#pragma unroll
    for (int n = 0; n < 4; n++) acc[m][n] = (f32x4){0.f, 0.f, 0.f, 0.f};

  // prologue: stage K(0) into Ks[0]
  {
    uint4 p0[4];
#pragma unroll
    for (int i = 0; i < 4; ++i)
      p0[i] = *(const uint4*)&Ktile[(size_t)(i * 256 + tid) * 8];
#pragma unroll
    for (int i = 0; i < 4; ++i)
      *(uint4*)&Ks[0][(i * 256 + tid) * 8] = p0[i];
  }
  __syncthreads();

  for (int it = 0; it < 64; ++it) {
    const int cur = it & 1;
    // ---- top clump: V(it) frags + K(it+1) stage loads ----
    bf16x8 vb[4];
#pragma unroll
    for (int n = 0; n < 4; ++n)
      vb[n] = *(const bf16x8*)&Vtile[(size_t)it * 8192 + (w * 64 + n * 16 + r15) * 32 + g * 8];
    uint4 st[4];
    if (it < 63) {
#pragma unroll
      for (int i = 0; i < 4; ++i)
        st[i] = *(const uint4*)&Ktile[(size_t)(it + 1) * 8192 + (i * 256 + tid) * 8];
    }

    // ---- QK^T: this wave's 32 s-rows x 32 t from Ks[cur] ----
#pragma unroll
    for (int h = 0; h < 2; ++h) {
      f32x4 gg[2];
      gg[0] = (f32x4){0.f, 0.f, 0.f, 0.f};
      gg[1] = (f32x4){0.f, 0.f, 0.f, 0.f};
#pragma unroll
      for (int n = 0; n < 2; ++n)
#pragma unroll
        for (int kk = 0; kk < 8; ++kk) {
          bf16x8 kb = *(const bf16x8*)&Ks[cur][(n * 16 + r15) * 256 + (((kk * 4 + g) ^ (r15 & 7)) << 3)];
          gg[n] = mfma16(q[h][kk], kb, gg[n]);
        }
#pragma unroll
      for (int n = 0; n < 2; ++n)
#pragma unroll
        for (int rr = 0; rr < 4; ++rr)
          Ps[cur][(w * 32 + h * 16 + g * 4 + rr) * 40 + n * 16 + r15] = f2bf(__expf(gg[n][rr]));
    }

    // ---- ds_write K(it+1): vmcnt wait covered by QK^T+exp above ----
    if (it < 63) {
#pragma unroll
      for (int i = 0; i < 4; ++i)
        *(uint4*)&Ks[cur ^ 1][(i * 256 + tid) * 8] = st[i];
    }

    __syncthreads();   // ONE barrier: Ps[cur]+Ks[cur^1] visible; prev reads done

    // ---- PV: all 128 s x this wave's 64 e ----
#pragma unroll
    for (int mh = 0; mh < 2; ++mh) {
      bf16x8 pa[4];
#pragma unroll
      for (int m = 0; m < 4; ++m)
        pa[m] = *(const bf16x8*)&Ps[cur][((mh * 4 + m) * 16 + r15) * 40 + g * 8];
#pragma unroll
      for (int n = 0; n < 4; ++n)
#pragma unroll
        for (int m = 0; m < 4; ++m)
          acc[mh * 4 + m][n] = mfma16(pa[m], vb[n], acc[mh * 4 + m][n]);
    }
  }

  const int b = bh >> 3, h = bh & 7;
#pragma unroll
  for (int m = 0; m < 8; m++)
#pragma unroll
    for (int n = 0; n < 4; n++)
#pragma unroll
      for (int rr = 0; rr < 4; rr++) {
        int sl = m * 16 + g * 4 + rr;
        int el = w * 64 + n * 16 + r15;
        Zb[((size_t)(b * 2048 + s0 + sl)) * 2048 + h * 256 + el] = f2bf(acc[m][n][rr]);
      }
}

// ---------------- V' in-place scale by 1/l_t (64 partials) ----------------
__global__ __launch_bounds__(256) void vscale(
    ushort* __restrict__ Vt, const float* __restrict__ lp)
{
  const int tt = blockIdx.x, bh = blockIdx.y, tid = threadIdx.x;
  const int t = tid & 31, pg = tid >> 5;
  __shared__ float red[256];
  __shared__ float cinv[32];
  float s = 0.f;
  for (int p = pg * 8; p < pg * 8 + 8; ++p)
    s += lp[(((size_t)p * 32 + bh) << 11) + tt * 32 + t];
  red[tid] = s;
  __syncthreads();
  if (tid < 32) {
    float tot = 0.f;
#pragma unroll
    for (int i = 0; i < 8; ++i) tot += red[tid + i * 32];
    cinv[tid] = 1.0f / tot;
  }
  __syncthreads();
  size_t base = (((size_t)bh * 64 + tt) << 13) + (size_t)tid * 32;
  ushort buf[32];
#pragma unroll
  for (int i = 0; i < 4; ++i) *(uint4*)&buf[i * 8] = *(const uint4*)&Vt[base + i * 8];
#pragma unroll
  for (int j = 0; j < 32; ++j) buf[j] = f2bf(bf2f(buf[j]) * cinv[j]);
#pragma unroll
  for (int i = 0; i < 4; ++i) *(uint4*)&Vt[base + i * 8] = *(const uint4*)&buf[i * 8];
}

// ---------------- launch ----------------
extern "C" void kernel_launch(void* const* d_in, const int* in_sizes, int n_in,
                              void* d_out, int out_size, void* d_ws, size_t ws_size,
                              hipStream_t stream) {
  const float* x  = (const float*)d_in[0];
  const float* Wq = (const float*)d_in[1];
  const float* bq = (const float*)d_in[2];
  const float* Wk = (const float*)d_in[3];
  const float* bk = (const float*)d_in[4];
  const float* Wv = (const float*)d_in[5];
  const float* bv = (const float*)d_in[6];
  const float* Wo = (const float*)d_in[7];
  const float* bo = (const float*)d_in[8];

  if (ws_size < (size_t)176160768) return; // need 168 MB scratch

  char* ws = (char*)d_ws;
  ushort* bfb = (ushort*)ws;                       // bf16 conversions (8 MB)
  ushort* xb  = bfb;
  ushort* wqb = bfb + 2097152;
  ushort* wkb = bfb + 2621440;
  ushort* wvb = bfb + 3145728;
  ushort* wob = bfb + 3670016;
  ushort* Qb = (ushort*)(ws + 8388608);            // [32,2048,256] (Q pre-scaled 1/16)
  ushort* Kb = (ushort*)(ws + 41943040);           // [32,2048,256] T2-swizzled
  ushort* Vt = (ushort*)(ws + 75497472);           // [32,64,256,32] tiled V'
  ushort* Zb = (ushort*)(ws + 109051904);          // [8192,2048]
  float*  lp = (float*)(ws + 142606336);           // [64,32,2048] fp32 partial colsums
  float* out = (float*)d_out;

  convert_all<<<4096, 256, 0, stream>>>(x, Wq, Wk, Wv, Wo, bfb);
  gemm_nt<128, 128, 0><<<dim3(48, 64), 256, 0, stream>>>(
      xb, wqb, wkb, wvb, 256, bq, bk, bv, Qb, Kb, Vt, nullptr);
  attn_p0<<<1024, 256, 0, stream>>>(Qb, Kb, lp);
  vscale<<<dim3(64, 32), 256, 0, stream>>>(Vt, lp);
  attn_p1<<<512, 256, 0, stream>>>(Qb, Kb, Vt, Zb);
  gemm_nt<64, 64, 1><<<dim3(4, 128), 256, 0, stream>>>(
      Zb, wob, wob, wob, 2048, bo, bo, bo, nullptr, nullptr, nullptr, out);
}

// Round 13
// 377.944 us; speedup vs baseline: 1.0997x; 1.0997x over previous
//
#include <hip/hip_runtime.h>
#include <hip/hip_bf16.h>

#define DEV __device__ __forceinline__

typedef __bf16 bf16x8 __attribute__((ext_vector_type(8)));
typedef float f32x4 __attribute__((ext_vector_type(4)));

DEV f32x4 mfma16(bf16x8 a, bf16x8 b, f32x4 c) {
  return __builtin_amdgcn_mfma_f32_16x16x32_bf16(a, b, c, 0, 0, 0);
}

DEV ushort f2bf(float f) {
  union { __hip_bfloat16 h; ushort u; } cv;
  cv.h = __float2bfloat16(f);
  return cv.u;
}
DEV float bf2f(ushort u) {
  union { float f; unsigned v; } cv; cv.v = ((unsigned)u) << 16; return cv.f;
}

// ---------------- constants ----------------
// B=4 H=8 S=2048 D=256; BH=32; M=B*S=8192
// K global layout: [bh][t][256] bf16, pre-swizzled: chunk(e>>3) ^= (t&7)  (T2 swizzle)
// V global layout: [bh][ttile=t/32][256 e][32 t] bf16 tiles (16KB), scaled by 1/l_t (vscale)
// lp: [128 partials (stile*4+w)][32 bh][2048 t] fp32
// NOTE: K staging reg-staged, NOT global_load_lds (r3 corruption).
// r11/r12 lesson: hipcc's occupancy-heuristic allocator spills long-live-range
//   prefetch regs regardless of launch_bounds (VGPR 60 + 270MB scratch both at
//   (256,4) and (256,3)). p0 s-tile-128 abandoned; r10 body restored (proven 130us).
// r13: dedicated out-GEMM with BK=64 (half the barriers/latency events).

// ---------------- kernel A: fp32 -> bf16 conversion ----------------
__global__ __launch_bounds__(256) void convert_all(
    const float* __restrict__ x, const float* __restrict__ wq,
    const float* __restrict__ wk, const float* __restrict__ wv,
    const float* __restrict__ wo, ushort* __restrict__ dst)
{
  size_t i = ((size_t)blockIdx.x * 256 + threadIdx.x) * 4;
  const float* src; size_t off;
  if (i < (size_t)2097152) { src = x; off = i; }
  else {
    size_t j = i - 2097152;
    unsigned wsel = (unsigned)(j >> 19);
    off = j & 524287;
    src = wsel == 0 ? wq : wsel == 1 ? wk : wsel == 2 ? wv : wo;
  }
  float4 v = *(const float4*)(src + off);
  ushort4 o;
  o.x = f2bf(v.x); o.y = f2bf(v.y); o.z = f2bf(v.z); o.w = f2bf(v.w);
  *(ushort4*)(dst + i) = o;
}

// ---------------- QKV GEMM (NT: A[M,K] row-major, Bt[N,K] row-major) ----------------
template<int BM, int BN>
__global__ __launch_bounds__(256, 2) void gemm_qkv(
    const ushort* __restrict__ A,
    const ushort* __restrict__ W0, const ushort* __restrict__ W1, const ushort* __restrict__ W2,
    int K,
    const float* __restrict__ b0, const float* __restrict__ b1, const float* __restrict__ b2,
    ushort* __restrict__ Qo, ushort* __restrict__ Ko, ushort* __restrict__ Vo)
{
  constexpr int WM = BM / 2, WN = BN / 2, MF = WM / 16, NF = WN / 16;
  constexpr int CA = BM / 64, CB = BN / 64;
  const int n0 = blockIdx.x * BN, m0 = blockIdx.y * BM;
  const int tid = threadIdx.x, lane = tid & 63;
  const int wm = (tid >> 7) & 1, wn = (tid >> 6) & 1;

  __shared__ ushort As[BM * 40];
  __shared__ ushort Bs[BN * 40];

  const int p = n0 >> 11;
  const ushort* Bt = (p == 0 ? W0 : p == 1 ? W1 : W2) + (size_t)(n0 & 2047) * K;

  f32x4 acc[MF][NF];
#pragma unroll
  for (int m = 0; m < MF; m++)
#pragma unroll
    for (int n = 0; n < NF; n++) acc[m][n] = (f32x4){0.f, 0.f, 0.f, 0.f};

  for (int k0 = 0; k0 < K; k0 += 32) {
#pragma unroll
    for (int i = 0; i < CA; i++) {
      int ci = tid * CA + i; int r = ci >> 2, c = ci & 3;
      *(uint4*)&As[r * 40 + c * 8] = *(const uint4*)&A[(size_t)(m0 + r) * K + k0 + c * 8];
    }
#pragma unroll
    for (int i = 0; i < CB; i++) {
      int ci = tid * CB + i; int r = ci >> 2, c = ci & 3;
      *(uint4*)&Bs[r * 40 + c * 8] = *(const uint4*)&Bt[(size_t)r * K + k0 + c * 8];
    }
    __syncthreads();
    bf16x8 af[MF], bfr[NF];
#pragma unroll
    for (int m = 0; m < MF; m++)
      af[m] = *(const bf16x8*)&As[(wm * WM + m * 16 + (lane & 15)) * 40 + ((lane >> 4) << 3)];
#pragma unroll
    for (int n = 0; n < NF; n++)
      bfr[n] = *(const bf16x8*)&Bs[(wn * WN + n * 16 + (lane & 15)) * 40 + ((lane >> 4) << 3)];
#pragma unroll
    for (int m = 0; m < MF; m++)
#pragma unroll
      for (int n = 0; n < NF; n++) acc[m][n] = mfma16(af[m], bfr[n], acc[m][n]);
    __syncthreads();
  }

  const float* bias = (p == 0 ? b0 : p == 1 ? b1 : b2);
  const float scl = (p == 0 ? 0.0625f : 1.0f);
#pragma unroll
  for (int m = 0; m < MF; m++)
#pragma unroll
    for (int n = 0; n < NF; n++)
#pragma unroll
      for (int r = 0; r < 4; r++) {
        int row = m0 + wm * WM + m * 16 + ((lane >> 4) << 2) + r;
        int col = n0 + wn * WN + n * 16 + (lane & 15);
        int ce = col & 2047;
        float v = (acc[m][n][r] + bias[ce]) * scl;
        int b = row >> 11, s = row & 2047, h = ce >> 8, e = ce & 255;
        int bh = b * 8 + h;
        if (p == 0) {
          Qo[((size_t)(bh * 2048 + s) << 8) + e] = f2bf(v);
        } else if (p == 1) {
          int ee = ((((e >> 3) ^ (s & 7)) & 31) << 3) | (e & 7); // T2 pre-swizzle
          Ko[((size_t)(bh * 2048 + s) << 8) + ee] = f2bf(v);
        } else {
          // tiled V': [bh][s>>5][e][s&31]
          Vo[(((size_t)bh * 64 + (s >> 5)) << 13) + e * 32 + (s & 31)] = f2bf(v);
        }
      }
}

// ---------------- out GEMM: [8192,2048] x Wo[256,2048]^T + bo -> fp32 [8192,256] ----------------
// BM=BN=64, BK=64: 8 MFMA per barrier-pair, 32 K-iters. grid (4,128)=512 = 2/CU.
__global__ __launch_bounds__(256, 2) void gemm_out(
    const ushort* __restrict__ A, const ushort* __restrict__ Bw,
    const float* __restrict__ bias, float* __restrict__ out)
{
  const int n0 = blockIdx.x * 64, m0 = blockIdx.y * 64;
  const int tid = threadIdx.x, lane = tid & 63;
  const int wm = (tid >> 7) & 1, wn = (tid >> 6) & 1;
  const int g = lane >> 4, r15 = lane & 15;

  __shared__ ushort As[64 * 72];
  __shared__ ushort Bs[64 * 72];

  f32x4 acc[2][2];
#pragma unroll
  for (int m = 0; m < 2; m++)
#pragma unroll
    for (int n = 0; n < 2; n++) acc[m][n] = (f32x4){0.f, 0.f, 0.f, 0.f};

  for (int k0 = 0; k0 < 2048; k0 += 64) {
#pragma unroll
    for (int i = 0; i < 2; ++i) {
      int ci = tid * 2 + i, r = ci >> 3, c = ci & 7;
      *(uint4*)&As[r * 72 + c * 8] = *(const uint4*)&A[(size_t)(m0 + r) * 2048 + k0 + c * 8];
      *(uint4*)&Bs[r * 72 + c * 8] = *(const uint4*)&Bw[(size_t)(n0 + r) * 2048 + k0 + c * 8];
    }
    __syncthreads();
    bf16x8 af[2][2], bfr[2][2];
#pragma unroll
    for (int m = 0; m < 2; ++m)
#pragma unroll
      for (int k2 = 0; k2 < 2; ++k2)
        af[m][k2] = *(const bf16x8*)&As[(wm * 32 + m * 16 + r15) * 72 + k2 * 32 + g * 8];
#pragma unroll
    for (int n = 0; n < 2; ++n)
#pragma unroll
      for (int k2 = 0; k2 < 2; ++k2)
        bfr[n][k2] = *(const bf16x8*)&Bs[(wn * 32 + n * 16 + r15) * 72 + k2 * 32 + g * 8];
#pragma unroll
    for (int k2 = 0; k2 < 2; ++k2)
#pragma unroll
      for (int m = 0; m < 2; ++m)
#pragma unroll
        for (int n = 0; n < 2; ++n)
          acc[m][n] = mfma16(af[m][k2], bfr[n][k2], acc[m][n]);
    __syncthreads();
  }

#pragma unroll
  for (int m = 0; m < 2; m++)
#pragma unroll
    for (int n = 0; n < 2; n++)
#pragma unroll
      for (int r = 0; r < 4; r++) {
        int row = m0 + wm * 32 + m * 16 + g * 4 + r;
        int col = n0 + wn * 32 + n * 16 + r15;
        out[(size_t)row * 256 + col] = acc[m][n][r] + bias[col];
      }
}

// ---------------- attention phase 0 (r10 exact, proven ~130us) ----------------
__global__ __launch_bounds__(256, 4) void attn_p0(
    const ushort* __restrict__ Qb, const ushort* __restrict__ Kb,
    float* __restrict__ lpart)
{
  const int bid = blockIdx.x;
  const int swz = (bid & 7) * 128 + (bid >> 3);
  const int bh = swz >> 5, stile = swz & 31;
  const int s0 = stile * 64;
  const int tid = threadIdx.x, lane = tid & 63, w = tid >> 6;
  const int g = lane >> 4, r15 = lane & 15;

  __shared__ ushort Ks[2][8192];

  bf16x8 q[8];
  {
    const ushort* qrow = &Qb[((size_t)bh * 2048 + s0 + w * 16 + r15) * 256 + g * 8];
#pragma unroll
    for (int kk = 0; kk < 8; kk++) q[kk] = *(const bf16x8*)&qrow[kk * 32];
  }

  const ushort* Ktile = Kb + ((size_t)bh << 19);

  uint4 st[4];
#pragma unroll
  for (int i = 0; i < 4; ++i)
    st[i] = *(const uint4*)&Ktile[(size_t)(i * 256 + tid) * 8];
#pragma unroll
  for (int i = 0; i < 4; ++i)
    *(uint4*)&Ks[0][(i * 256 + tid) * 8] = st[i];

  int cur = 0;
  for (int it = 0; it < 64; ++it) {
    __syncthreads();
    if (it < 63) {
#pragma unroll
      for (int i = 0; i < 4; ++i)
        st[i] = *(const uint4*)&Ktile[(size_t)(it + 1) * 8192 + (i * 256 + tid) * 8];
    }
    f32x4 gg[2];
    gg[0] = (f32x4){0.f, 0.f, 0.f, 0.f};
    gg[1] = (f32x4){0.f, 0.f, 0.f, 0.f};
    const ushort* ks = &Ks[cur][0];
#pragma unroll
    for (int n = 0; n < 2; ++n)
#pragma unroll
      for (int kk = 0; kk < 8; ++kk) {
        bf16x8 kb = *(const bf16x8*)&ks[(n * 16 + r15) * 256 + (((kk * 4 + g) ^ (r15 & 7)) << 3)];
        gg[n] = mfma16(q[kk], kb, gg[n]);
      }
#pragma unroll
    for (int n = 0; n < 2; ++n) {
      float sn = __expf(gg[n][0]) + __expf(gg[n][1]) + __expf(gg[n][2]) + __expf(gg[n][3]);
      sn += __shfl_xor(sn, 16);
      sn += __shfl_xor(sn, 32);
      if (g == 0)
        lpart[((size_t)((stile * 4 + w) * 32 + bh) << 11) + it * 32 + n * 16 + r15] = sn;
    }
    if (it < 63) {
#pragma unroll
      for (int i = 0; i < 4; ++i)
        *(uint4*)&Ks[cur ^ 1][(i * 256 + tid) * 8] = st[i];
    }
    cur ^= 1;
  }
}

// ---------------- attention phase 1: s-tile 128 + one-barrier pipeline (r10, proven) ----------------
__global__ __launch_bounds__(256, 2) void attn_p1(
    const ushort* __restrict__ Qb, const ushort* __restrict__ Kb,
    const ushort* __restrict__ Vt, ushort* __restrict__ Zb)
{
  const int bid = blockIdx.x;
  const int swz = (bid & 7) * 64 + (bid >> 3);   // bijective: 512 % 8 == 0
  const int bh = swz >> 4, stile = swz & 15;
  const int s0 = stile * 128;
  const int tid = threadIdx.x, lane = tid & 63, w = tid >> 6;
  const int g = lane >> 4, r15 = lane & 15;

  __shared__ __align__(16) ushort Ks[2][8192];   // dbuf K tile [32 t][256 k], swizzled
  __shared__ __align__(16) ushort Ps[2][5120];   // dbuf [128 s][40]

  bf16x8 q[2][8];
#pragma unroll
  for (int h = 0; h < 2; ++h) {
    const ushort* qrow = &Qb[((size_t)bh * 2048 + s0 + w * 32 + h * 16 + r15) * 256 + g * 8];
#pragma unroll
    for (int kk = 0; kk < 8; kk++) q[h][kk] = *(const bf16x8*)&qrow[kk * 32];
  }

  const ushort* Ktile = Kb + ((size_t)bh << 19);
  const ushort* Vtile = Vt + ((size_t)bh << 19);

  f32x4 acc[8][4];
#pragma unroll
  for (int m = 0; m < 8; m++)
#pragma unroll
    for (int n = 0; n < 4; n++) acc[m][n] = (f32x4){0.f, 0.f, 0.f, 0.f};

  // prologue: stage K(0) into Ks[0]
  {
    uint4 p0[4];
#pragma unroll
    for (int i = 0; i < 4; ++i)
      p0[i] = *(const uint4*)&Ktile[(size_t)(i * 256 + tid) * 8];
#pragma unroll
    for (int i = 0; i < 4; ++i)
      *(uint4*)&Ks[0][(i * 256 + tid) * 8] = p0[i];
  }
  __syncthreads();

  for (int it = 0; it < 64; ++it) {
    const int cur = it & 1;
    // ---- top clump: V(it) frags + K(it+1) stage loads ----
    bf16x8 vb[4];
#pragma unroll
    for (int n = 0; n < 4; ++n)
      vb[n] = *(const bf16x8*)&Vtile[(size_t)it * 8192 + (w * 64 + n * 16 + r15) * 32 + g * 8];
    uint4 st[4];
    if (it < 63) {
#pragma unroll
      for (int i = 0; i < 4; ++i)
        st[i] = *(const uint4*)&Ktile[(size_t)(it + 1) * 8192 + (i * 256 + tid) * 8];
    }

    // ---- QK^T: this wave's 32 s-rows x 32 t from Ks[cur] ----
#pragma unroll
    for (int h = 0; h < 2; ++h) {
      f32x4 gg[2];
      gg[0] = (f32x4){0.f, 0.f, 0.f, 0.f};
      gg[1] = (f32x4){0.f, 0.f, 0.f, 0.f};
#pragma unroll
      for (int n = 0; n < 2; ++n)
#pragma unroll
        for (int kk = 0; kk < 8; ++kk) {
          bf16x8 kb = *(const bf16x8*)&Ks[cur][(n * 16 + r15) * 256 + (((kk * 4 + g) ^ (r15 & 7)) << 3)];
          gg[n] = mfma16(q[h][kk], kb, gg[n]);
        }
#pragma unroll
      for (int n = 0; n < 2; ++n)
#pragma unroll
        for (int rr = 0; rr < 4; ++rr)
          Ps[cur][(w * 32 + h * 16 + g * 4 + rr) * 40 + n * 16 + r15] = f2bf(__expf(gg[n][rr]));
    }

    // ---- ds_write K(it+1): vmcnt wait covered by QK^T+exp above ----
    if (it < 63) {
#pragma unroll
      for (int i = 0; i < 4; ++i)
        *(uint4*)&Ks[cur ^ 1][(i * 256 + tid) * 8] = st[i];
    }

    __syncthreads();   // ONE barrier: Ps[cur]+Ks[cur^1] visible; prev reads done

    // ---- PV: all 128 s x this wave's 64 e ----
#pragma unroll
    for (int mh = 0; mh < 2; ++mh) {
      bf16x8 pa[4];
#pragma unroll
      for (int m = 0; m < 4; ++m)
        pa[m] = *(const bf16x8*)&Ps[cur][((mh * 4 + m) * 16 + r15) * 40 + g * 8];
#pragma unroll
      for (int n = 0; n < 4; ++n)
#pragma unroll
        for (int m = 0; m < 4; ++m)
          acc[mh * 4 + m][n] = mfma16(pa[m], vb[n], acc[mh * 4 + m][n]);
    }
  }

  const int b = bh >> 3, h = bh & 7;
#pragma unroll
  for (int m = 0; m < 8; m++)
#pragma unroll
    for (int n = 0; n < 4; n++)
#pragma unroll
      for (int rr = 0; rr < 4; rr++) {
        int sl = m * 16 + g * 4 + rr;
        int el = w * 64 + n * 16 + r15;
        Zb[((size_t)(b * 2048 + s0 + sl)) * 2048 + h * 256 + el] = f2bf(acc[m][n][rr]);
      }
}

// ---------------- V' in-place scale by 1/l_t (128 partials, r10 exact) ----------------
__global__ __launch_bounds__(256) void vscale(
    ushort* __restrict__ Vt, const float* __restrict__ lp)
{
  const int tt = blockIdx.x, bh = blockIdx.y, tid = threadIdx.x;
  const int t = tid & 31, pg = tid >> 5;
  __shared__ float red[256];
  __shared__ float cinv[32];
  float s = 0.f;
  for (int p = pg * 16; p < pg * 16 + 16; ++p)
    s += lp[(((size_t)p * 32 + bh) << 11) + tt * 32 + t];
  red[tid] = s;
  __syncthreads();
  if (tid < 32) {
    float tot = 0.f;
#pragma unroll
    for (int i = 0; i < 8; ++i) tot += red[tid + i * 32];
    cinv[tid] = 1.0f / tot;
  }
  __syncthreads();
  size_t base = (((size_t)bh * 64 + tt) << 13) + (size_t)tid * 32;
  ushort buf[32];
#pragma unroll
  for (int i = 0; i < 4; ++i) *(uint4*)&buf[i * 8] = *(const uint4*)&Vt[base + i * 8];
#pragma unroll
  for (int j = 0; j < 32; ++j) buf[j] = f2bf(bf2f(buf[j]) * cinv[j]);
#pragma unroll
  for (int i = 0; i < 4; ++i) *(uint4*)&Vt[base + i * 8] = *(const uint4*)&buf[i * 8];
}

// ---------------- launch ----------------
extern "C" void kernel_launch(void* const* d_in, const int* in_sizes, int n_in,
                              void* d_out, int out_size, void* d_ws, size_t ws_size,
                              hipStream_t stream) {
  const float* x  = (const float*)d_in[0];
  const float* Wq = (const float*)d_in[1];
  const float* bq = (const float*)d_in[2];
  const float* Wk = (const float*)d_in[3];
  const float* bk = (const float*)d_in[4];
  const float* Wv = (const float*)d_in[5];
  const float* bv = (const float*)d_in[6];
  const float* Wo = (const float*)d_in[7];
  const float* bo = (const float*)d_in[8];

  if (ws_size < (size_t)176160768) return; // need 168 MB scratch

  char* ws = (char*)d_ws;
  ushort* bfb = (ushort*)ws;                       // bf16 conversions (8 MB)
  ushort* xb  = bfb;
  ushort* wqb = bfb + 2097152;
  ushort* wkb = bfb + 2621440;
  ushort* wvb = bfb + 3145728;
  ushort* wob = bfb + 3670016;
  ushort* Qb = (ushort*)(ws + 8388608);            // [32,2048,256] (Q pre-scaled 1/16)
  ushort* Kb = (ushort*)(ws + 41943040);           // [32,2048,256] T2-swizzled
  ushort* Vt = (ushort*)(ws + 75497472);           // [32,64,256,32] tiled V'
  ushort* Zb = (ushort*)(ws + 109051904);          // [8192,2048]
  float*  lp = (float*)(ws + 142606336);           // [128,32,2048] fp32 partial colsums
  float* out = (float*)d_out;

  convert_all<<<4096, 256, 0, stream>>>(x, Wq, Wk, Wv, Wo, bfb);
  gemm_qkv<128, 128><<<dim3(48, 64), 256, 0, stream>>>(
      xb, wqb, wkb, wvb, 256, bq, bk, bv, Qb, Kb, Vt);
  attn_p0<<<1024, 256, 0, stream>>>(Qb, Kb, lp);
  vscale<<<dim3(64, 32), 256, 0, stream>>>(Vt, lp);
  attn_p1<<<512, 256, 0, stream>>>(Qb, Kb, Vt, Zb);
  gemm_out<<<dim3(4, 128), 256, 0, stream>>>(Zb, wob, bo, out);
}

// Round 15
// 346.964 us; speedup vs baseline: 1.1979x; 1.0893x over previous
//
#include <hip/hip_runtime.h>
#include <hip/hip_bf16.h>

#define DEV __device__ __forceinline__

typedef __bf16 bf16x8 __attribute__((ext_vector_type(8)));
typedef float f32x4 __attribute__((ext_vector_type(4)));

DEV f32x4 mfma16(bf16x8 a, bf16x8 b, f32x4 c) {
  return __builtin_amdgcn_mfma_f32_16x16x32_bf16(a, b, c, 0, 0, 0);
}

DEV ushort f2bf(float f) {
  union { __hip_bfloat16 h; ushort u; } cv;
  cv.h = __float2bfloat16(f);
  return cv.u;
}
DEV float bf2f(ushort u) {
  union { float f; unsigned v; } cv; cv.v = ((unsigned)u) << 16; return cv.f;
}

// ---------------- constants ----------------
// B=4 H=8 S=2048 D=256; BH=32; M=B*S=8192
// K global layout: [bh][t][256] bf16, pre-swizzled: chunk(e>>3) ^= (t&7)  (T2 swizzle)
// V global layout: [bh][ttile=t/32][256 e][32 t] bf16 tiles (16KB), scaled by 1/l_t (vscale)
// lp: [64 partials (stile*4+w)][32 bh][2048 t] fp32  (16 stiles x 4 waves)
// NOTE: K staging reg-staged, NOT global_load_lds (r3 corruption).
// r11/r12 lesson: hipcc remats q + spills cold st to hit the 64-reg/8-wave
//   boundary. Countermeasures in p0: single-buffer (st short-lived), per-n
//   accumulators, q pinned via opaque empty asm. r14 lesson: "+v" ties must be
//   on 32-bit components, not uint4 tuples ("tied indirect register inputs").

// ---------------- kernel A: fp32 -> bf16 conversion ----------------
__global__ __launch_bounds__(256) void convert_all(
    const float* __restrict__ x, const float* __restrict__ wq,
    const float* __restrict__ wk, const float* __restrict__ wv,
    const float* __restrict__ wo, ushort* __restrict__ dst)
{
  size_t i = ((size_t)blockIdx.x * 256 + threadIdx.x) * 4;
  const float* src; size_t off;
  if (i < (size_t)2097152) { src = x; off = i; }
  else {
    size_t j = i - 2097152;
    unsigned wsel = (unsigned)(j >> 19);
    off = j & 524287;
    src = wsel == 0 ? wq : wsel == 1 ? wk : wsel == 2 ? wv : wo;
  }
  float4 v = *(const float4*)(src + off);
  ushort4 o;
  o.x = f2bf(v.x); o.y = f2bf(v.y); o.z = f2bf(v.z); o.w = f2bf(v.w);
  *(ushort4*)(dst + i) = o;
}

// ---------------- QKV GEMM (NT: A[M,K] row-major, Bt[N,K] row-major) ----------------
template<int BM, int BN>
__global__ __launch_bounds__(256, 2) void gemm_qkv(
    const ushort* __restrict__ A,
    const ushort* __restrict__ W0, const ushort* __restrict__ W1, const ushort* __restrict__ W2,
    int K,
    const float* __restrict__ b0, const float* __restrict__ b1, const float* __restrict__ b2,
    ushort* __restrict__ Qo, ushort* __restrict__ Ko, ushort* __restrict__ Vo)
{
  constexpr int WM = BM / 2, WN = BN / 2, MF = WM / 16, NF = WN / 16;
  constexpr int CA = BM / 64, CB = BN / 64;
  const int n0 = blockIdx.x * BN, m0 = blockIdx.y * BM;
  const int tid = threadIdx.x, lane = tid & 63;
  const int wm = (tid >> 7) & 1, wn = (tid >> 6) & 1;

  __shared__ ushort As[BM * 40];
  __shared__ ushort Bs[BN * 40];

  const int p = n0 >> 11;
  const ushort* Bt = (p == 0 ? W0 : p == 1 ? W1 : W2) + (size_t)(n0 & 2047) * K;

  f32x4 acc[MF][NF];
#pragma unroll
  for (int m = 0; m < MF; m++)
#pragma unroll
    for (int n = 0; n < NF; n++) acc[m][n] = (f32x4){0.f, 0.f, 0.f, 0.f};

  for (int k0 = 0; k0 < K; k0 += 32) {
#pragma unroll
    for (int i = 0; i < CA; i++) {
      int ci = tid * CA + i; int r = ci >> 2, c = ci & 3;
      *(uint4*)&As[r * 40 + c * 8] = *(const uint4*)&A[(size_t)(m0 + r) * K + k0 + c * 8];
    }
#pragma unroll
    for (int i = 0; i < CB; i++) {
      int ci = tid * CB + i; int r = ci >> 2, c = ci & 3;
      *(uint4*)&Bs[r * 40 + c * 8] = *(const uint4*)&Bt[(size_t)r * K + k0 + c * 8];
    }
    __syncthreads();
    bf16x8 af[MF], bfr[NF];
#pragma unroll
    for (int m = 0; m < MF; m++)
      af[m] = *(const bf16x8*)&As[(wm * WM + m * 16 + (lane & 15)) * 40 + ((lane >> 4) << 3)];
#pragma unroll
    for (int n = 0; n < NF; n++)
      bfr[n] = *(const bf16x8*)&Bs[(wn * WN + n * 16 + (lane & 15)) * 40 + ((lane >> 4) << 3)];
#pragma unroll
    for (int m = 0; m < MF; m++)
#pragma unroll
      for (int n = 0; n < NF; n++) acc[m][n] = mfma16(af[m], bfr[n], acc[m][n]);
    __syncthreads();
  }

  const float* bias = (p == 0 ? b0 : p == 1 ? b1 : b2);
  const float scl = (p == 0 ? 0.0625f : 1.0f);
#pragma unroll
  for (int m = 0; m < MF; m++)
#pragma unroll
    for (int n = 0; n < NF; n++)
#pragma unroll
      for (int r = 0; r < 4; r++) {
        int row = m0 + wm * WM + m * 16 + ((lane >> 4) << 2) + r;
        int col = n0 + wn * WN + n * 16 + (lane & 15);
        int ce = col & 2047;
        float v = (acc[m][n][r] + bias[ce]) * scl;
        int b = row >> 11, s = row & 2047, h = ce >> 8, e = ce & 255;
        int bh = b * 8 + h;
        if (p == 0) {
          Qo[((size_t)(bh * 2048 + s) << 8) + e] = f2bf(v);
        } else if (p == 1) {
          int ee = ((((e >> 3) ^ (s & 7)) & 31) << 3) | (e & 7); // T2 pre-swizzle
          Ko[((size_t)(bh * 2048 + s) << 8) + ee] = f2bf(v);
        } else {
          // tiled V': [bh][s>>5][e][s&31]
          Vo[(((size_t)bh * 64 + (s >> 5)) << 13) + e * 32 + (s & 31)] = f2bf(v);
        }
      }
}

// ---------------- out GEMM: [8192,2048] x Wo[256,2048]^T + bo -> fp32 [8192,256] ----------------
__global__ __launch_bounds__(256, 2) void gemm_out(
    const ushort* __restrict__ A, const ushort* __restrict__ Bw,
    const float* __restrict__ bias, float* __restrict__ out)
{
  const int n0 = blockIdx.x * 64, m0 = blockIdx.y * 64;
  const int tid = threadIdx.x, lane = tid & 63;
  const int wm = (tid >> 7) & 1, wn = (tid >> 6) & 1;
  const int g = lane >> 4, r15 = lane & 15;

  __shared__ ushort As[64 * 72];
  __shared__ ushort Bs[64 * 72];

  f32x4 acc[2][2];
#pragma unroll
  for (int m = 0; m < 2; m++)
#pragma unroll
    for (int n = 0; n < 2; n++) acc[m][n] = (f32x4){0.f, 0.f, 0.f, 0.f};

  for (int k0 = 0; k0 < 2048; k0 += 64) {
#pragma unroll
    for (int i = 0; i < 2; ++i) {
      int ci = tid * 2 + i, r = ci >> 3, c = ci & 7;
      *(uint4*)&As[r * 72 + c * 8] = *(const uint4*)&A[(size_t)(m0 + r) * 2048 + k0 + c * 8];
      *(uint4*)&Bs[r * 72 + c * 8] = *(const uint4*)&Bw[(size_t)(n0 + r) * 2048 + k0 + c * 8];
    }
    __syncthreads();
    bf16x8 af[2][2], bfr[2][2];
#pragma unroll
    for (int m = 0; m < 2; ++m)
#pragma unroll
      for (int k2 = 0; k2 < 2; ++k2)
        af[m][k2] = *(const bf16x8*)&As[(wm * 32 + m * 16 + r15) * 72 + k2 * 32 + g * 8];
#pragma unroll
    for (int n = 0; n < 2; ++n)
#pragma unroll
      for (int k2 = 0; k2 < 2; ++k2)
        bfr[n][k2] = *(const bf16x8*)&Bs[(wn * 32 + n * 16 + r15) * 72 + k2 * 32 + g * 8];
#pragma unroll
    for (int k2 = 0; k2 < 2; ++k2)
#pragma unroll
      for (int m = 0; m < 2; ++m)
#pragma unroll
        for (int n = 0; n < 2; ++n)
          acc[m][n] = mfma16(af[m][k2], bfr[n][k2], acc[m][n]);
    __syncthreads();
  }

#pragma unroll
  for (int m = 0; m < 2; m++)
#pragma unroll
    for (int n = 0; n < 2; n++)
#pragma unroll
      for (int r = 0; r < 4; r++) {
        int row = m0 + wm * 32 + m * 16 + g * 4 + r;
        int col = n0 + wn * 32 + n * 16 + r15;
        out[(size_t)row * 256 + col] = acc[m][n][r] + bias[col];
      }
}

// ---------------- attention phase 0: s-tile 128, t-halved, single-buffer ----------------
// grid 1024 XCD-swizzled (32bh x 16stile x 2 thalf) = 4 blocks/CU.
// Per iter: clump 4 K loads -> ds_write (st short-lived) -> barrier ->
// shared-kb QK^T (each frag feeds both q halves) + exp/colsum -> barrier.
// q pinned via opaque per-component asm so the allocator can't rematerialize it.
__global__ __launch_bounds__(256, 4) void attn_p0(
    const ushort* __restrict__ Qb, const ushort* __restrict__ Kb,
    float* __restrict__ lpart)
{
  const int bid = blockIdx.x;
  const int swz = (bid & 7) * 128 + (bid >> 3);   // bijective: 1024 % 8 == 0
  const int bh = swz >> 5, stile = (swz >> 1) & 15, half = swz & 1;
  const int s0 = stile * 128;
  const int tid = threadIdx.x, lane = tid & 63, w = tid >> 6;
  const int g = lane >> 4, r15 = lane & 15;

  __shared__ __align__(16) ushort Ks[8192];   // [32 t][256 k] single buffer, swizzled

  uint4 qr[2][8];
#pragma unroll
  for (int h = 0; h < 2; ++h) {
    const ushort* qrow = &Qb[((size_t)bh * 2048 + s0 + w * 32 + h * 16 + r15) * 256 + g * 8];
#pragma unroll
    for (int kk = 0; kk < 8; kk++) qr[h][kk] = *(const uint4*)&qrow[kk * 32];
  }
  // pin q: opaque to rematerialization (per-32-bit-component ties; uint4 ties
  // don't compile on AMDGPU — r14)
#pragma unroll
  for (int h = 0; h < 2; ++h)
#pragma unroll
    for (int kk = 0; kk < 8; kk++)
      asm volatile("" : "+v"(qr[h][kk].x), "+v"(qr[h][kk].y),
                        "+v"(qr[h][kk].z), "+v"(qr[h][kk].w));

  const ushort* Ktile = Kb + ((size_t)bh << 19);
  const int it0 = half * 32, it1 = it0 + 32;

  for (int it = it0; it < it1; ++it) {
    uint4 st[4];
#pragma unroll
    for (int i = 0; i < 4; ++i)
      st[i] = *(const uint4*)&Ktile[(size_t)it * 8192 + (i * 256 + tid) * 8];
#pragma unroll
    for (int i = 0; i < 4; ++i)
      *(uint4*)&Ks[(i * 256 + tid) * 8] = st[i];
    __syncthreads();   // Ks visible

#pragma unroll
    for (int n = 0; n < 2; ++n) {
      f32x4 g0 = (f32x4){0.f, 0.f, 0.f, 0.f};
      f32x4 g1 = (f32x4){0.f, 0.f, 0.f, 0.f};
#pragma unroll
      for (int kk = 0; kk < 8; ++kk) {
        bf16x8 kb = *(const bf16x8*)&Ks[(n * 16 + r15) * 256 + (((kk * 4 + g) ^ (r15 & 7)) << 3)];
        g0 = mfma16(*(const bf16x8*)&qr[0][kk], kb, g0);
        g1 = mfma16(*(const bf16x8*)&qr[1][kk], kb, g1);
      }
      float sn = __expf(g0[0]) + __expf(g0[1]) + __expf(g0[2]) + __expf(g0[3])
               + __expf(g1[0]) + __expf(g1[1]) + __expf(g1[2]) + __expf(g1[3]);
      sn += __shfl_xor(sn, 16);
      sn += __shfl_xor(sn, 32);
      if (g == 0)
        lpart[((size_t)((stile * 4 + w) * 32 + bh) << 11) + it * 32 + n * 16 + r15] = sn;
    }
    __syncthreads();   // reads done before next iter's writes
  }
}

// ---------------- attention phase 1: s-tile 128 + one-barrier pipeline ----------------
// r10 structure + per-n kb-sharing (each K-frag ds_read once, feeds both q halves).
__global__ __launch_bounds__(256, 2) void attn_p1(
    const ushort* __restrict__ Qb, const ushort* __restrict__ Kb,
    const ushort* __restrict__ Vt, ushort* __restrict__ Zb)
{
  const int bid = blockIdx.x;
  const int swz = (bid & 7) * 64 + (bid >> 3);   // bijective: 512 % 8 == 0
  const int bh = swz >> 4, stile = swz & 15;
  const int s0 = stile * 128;
  const int tid = threadIdx.x, lane = tid & 63, w = tid >> 6;
  const int g = lane >> 4, r15 = lane & 15;

  __shared__ __align__(16) ushort Ks[2][8192];   // dbuf K tile [32 t][256 k], swizzled
  __shared__ __align__(16) ushort Ps[2][5120];   // dbuf [128 s][40]

  bf16x8 q[2][8];
#pragma unroll
  for (int h = 0; h < 2; ++h) {
    const ushort* qrow = &Qb[((size_t)bh * 2048 + s0 + w * 32 + h * 16 + r15) * 256 + g * 8];
#pragma unroll
    for (int kk = 0; kk < 8; kk++) q[h][kk] = *(const bf16x8*)&qrow[kk * 32];
  }

  const ushort* Ktile = Kb + ((size_t)bh << 19);
  const ushort* Vtile = Vt + ((size_t)bh << 19);

  f32x4 acc[8][4];
#pragma unroll
  for (int m = 0; m < 8; m++)
#pragma unroll
    for (int n = 0; n < 4; n++) acc[m][n] = (f32x4){0.f, 0.f, 0.f, 0.f};

  // prologue: stage K(0) into Ks[0]
  {
    uint4 p0[4];
#pragma unroll
    for (int i = 0; i < 4; ++i)
      p0[i] = *(const uint4*)&Ktile[(size_t)(i * 256 + tid) * 8];
#pragma unroll
    for (int i = 0; i < 4; ++i)
      *(uint4*)&Ks[0][(i * 256 + tid) * 8] = p0[i];
  }
  __syncthreads();

  for (int it = 0; it < 64; ++it) {
    const int cur = it & 1;
    // ---- top clump: V(it) frags + K(it+1) stage loads ----
    bf16x8 vb[4];
#pragma unroll
    for (int n = 0; n < 4; ++n)
      vb[n] = *(const bf16x8*)&Vtile[(size_t)it * 8192 + (w * 64 + n * 16 + r15) * 32 + g * 8];
    uint4 st[4];
    if (it < 63) {
#pragma unroll
      for (int i = 0; i < 4; ++i)
        st[i] = *(const uint4*)&Ktile[(size_t)(it + 1) * 8192 + (i * 256 + tid) * 8];
    }

    // ---- QK^T: per-n shared kb; this wave's 32 s-rows x 32 t from Ks[cur] ----
#pragma unroll
    for (int n = 0; n < 2; ++n) {
      f32x4 g0 = (f32x4){0.f, 0.f, 0.f, 0.f};
      f32x4 g1 = (f32x4){0.f, 0.f, 0.f, 0.f};
#pragma unroll
      for (int kk = 0; kk < 8; ++kk) {
        bf16x8 kb = *(const bf16x8*)&Ks[cur][(n * 16 + r15) * 256 + (((kk * 4 + g) ^ (r15 & 7)) << 3)];
        g0 = mfma16(q[0][kk], kb, g0);
        g1 = mfma16(q[1][kk], kb, g1);
      }
#pragma unroll
      for (int rr = 0; rr < 4; ++rr) {
        Ps[cur][(w * 32 + g * 4 + rr) * 40 + n * 16 + r15] = f2bf(__expf(g0[rr]));
        Ps[cur][(w * 32 + 16 + g * 4 + rr) * 40 + n * 16 + r15] = f2bf(__expf(g1[rr]));
      }
    }

    // ---- ds_write K(it+1): vmcnt wait covered by QK^T+exp above ----
    if (it < 63) {
#pragma unroll
      for (int i = 0; i < 4; ++i)
        *(uint4*)&Ks[cur ^ 1][(i * 256 + tid) * 8] = st[i];
    }

    __syncthreads();   // ONE barrier: Ps[cur]+Ks[cur^1] visible; prev reads done

    // ---- PV: all 128 s x this wave's 64 e ----
#pragma unroll
    for (int mh = 0; mh < 2; ++mh) {
      bf16x8 pa[4];
#pragma unroll
      for (int m = 0; m < 4; ++m)
        pa[m] = *(const bf16x8*)&Ps[cur][((mh * 4 + m) * 16 + r15) * 40 + g * 8];
#pragma unroll
      for (int n = 0; n < 4; ++n)
#pragma unroll
        for (int m = 0; m < 4; ++m)
          acc[mh * 4 + m][n] = mfma16(pa[m], vb[n], acc[mh * 4 + m][n]);
    }
  }

  const int b = bh >> 3, h = bh & 7;
#pragma unroll
  for (int m = 0; m < 8; m++)
#pragma unroll
    for (int n = 0; n < 4; n++)
#pragma unroll
      for (int rr = 0; rr < 4; rr++) {
        int sl = m * 16 + g * 4 + rr;
        int el = w * 64 + n * 16 + r15;
        Zb[((size_t)(b * 2048 + s0 + sl)) * 2048 + h * 256 + el] = f2bf(acc[m][n][rr]);
      }
}

// ---------------- V' in-place scale by 1/l_t (64 partials) ----------------
__global__ __launch_bounds__(256) void vscale(
    ushort* __restrict__ Vt, const float* __restrict__ lp)
{
  const int tt = blockIdx.x, bh = blockIdx.y, tid = threadIdx.x;
  const int t = tid & 31, pg = tid >> 5;
  __shared__ float red[256];
  __shared__ float cinv[32];
  float s = 0.f;
  for (int p = pg * 8; p < pg * 8 + 8; ++p)
    s += lp[(((size_t)p * 32 + bh) << 11) + tt * 32 + t];
  red[tid] = s;
  __syncthreads();
  if (tid < 32) {
    float tot = 0.f;
#pragma unroll
    for (int i = 0; i < 8; ++i) tot += red[tid + i * 32];
    cinv[tid] = 1.0f / tot;
  }
  __syncthreads();
  size_t base = (((size_t)bh * 64 + tt) << 13) + (size_t)tid * 32;
  ushort buf[32];
#pragma unroll
  for (int i = 0; i < 4; ++i) *(uint4*)&buf[i * 8] = *(const uint4*)&Vt[base + i * 8];
#pragma unroll
  for (int j = 0; j < 32; ++j) buf[j] = f2bf(bf2f(buf[j]) * cinv[j]);
#pragma unroll
  for (int i = 0; i < 4; ++i) *(uint4*)&Vt[base + i * 8] = *(const uint4*)&buf[i * 8];
}

// ---------------- launch ----------------
extern "C" void kernel_launch(void* const* d_in, const int* in_sizes, int n_in,
                              void* d_out, int out_size, void* d_ws, size_t ws_size,
                              hipStream_t stream) {
  const float* x  = (const float*)d_in[0];
  const float* Wq = (const float*)d_in[1];
  const float* bq = (const float*)d_in[2];
  const float* Wk = (const float*)d_in[3];
  const float* bk = (const float*)d_in[4];
  const float* Wv = (const float*)d_in[5];
  const float* bv = (const float*)d_in[6];
  const float* Wo = (const float*)d_in[7];
  const float* bo = (const float*)d_in[8];

  if (ws_size < (size_t)176160768) return; // need 168 MB scratch

  char* ws = (char*)d_ws;
  ushort* bfb = (ushort*)ws;                       // bf16 conversions (8 MB)
  ushort* xb  = bfb;
  ushort* wqb = bfb + 2097152;
  ushort* wkb = bfb + 2621440;
  ushort* wvb = bfb + 3145728;
  ushort* wob = bfb + 3670016;
  ushort* Qb = (ushort*)(ws + 8388608);            // [32,2048,256] (Q pre-scaled 1/16)
  ushort* Kb = (ushort*)(ws + 41943040);           // [32,2048,256] T2-swizzled
  ushort* Vt = (ushort*)(ws + 75497472);           // [32,64,256,32] tiled V'
  ushort* Zb = (ushort*)(ws + 109051904);          // [8192,2048]
  float*  lp = (float*)(ws + 142606336);           // [64,32,2048] fp32 partial colsums
  float* out = (float*)d_out;

  convert_all<<<4096, 256, 0, stream>>>(x, Wq, Wk, Wv, Wo, bfb);
  gemm_qkv<128, 128><<<dim3(48, 64), 256, 0, stream>>>(
      xb, wqb, wkb, wvb, 256, bq, bk, bv, Qb, Kb, Vt);
  attn_p0<<<1024, 256, 0, stream>>>(Qb, Kb, lp);
  vscale<<<dim3(64, 32), 256, 0, stream>>>(Vt, lp);
  attn_p1<<<512, 256, 0, stream>>>(Qb, Kb, Vt, Zb);
  gemm_out<<<dim3(4, 128), 256, 0, stream>>>(Zb, wob, bo, out);
}

// Round 16
// 339.166 us; speedup vs baseline: 1.2255x; 1.0230x over previous
//
#include <hip/hip_runtime.h>
#include <hip/hip_bf16.h>

#define DEV __device__ __forceinline__

typedef __bf16 bf16x8 __attribute__((ext_vector_type(8)));
typedef float f32x4 __attribute__((ext_vector_type(4)));

DEV f32x4 mfma16(bf16x8 a, bf16x8 b, f32x4 c) {
  return __builtin_amdgcn_mfma_f32_16x16x32_bf16(a, b, c, 0, 0, 0);
}

DEV ushort f2bf(float f) {
  union { __hip_bfloat16 h; ushort u; } cv;
  cv.h = __float2bfloat16(f);
  return cv.u;
}
DEV float bf2f(ushort u) {
  union { float f; unsigned v; } cv; cv.v = ((unsigned)u) << 16; return cv.f;
}

// ---------------- constants ----------------
// B=4 H=8 S=2048 D=256; BH=32; M=B*S=8192
// K global layout: [bh][t][256] bf16, pre-swizzled: chunk(e>>3) ^= (t&7)  (T2 swizzle)
// V global layout: [bh][ttile=t/32][256 e][32 t] bf16 tiles (16KB), scaled by 1/l_t (vscale)
// lp: [64 partials (stile*4+w)][32 bh][2048 t] fp32  (16 stiles x 4 waves)
// NOTE: K staging reg-staged, NOT global_load_lds (r3 corruption).
// r15 lessons: (a) q-pin via per-component "+v" asm defeats hipcc's remat+spill
//   heuristic — p0 s-tile-128 now works (~100us). (b) p1 per-n kb-sharing
//   REGRESSED (143->153): ds_reads weren't the bottleneck; reverted to r10 QK^T.
// r16: gemm_qkv BK 32->64 (4 K-iters, 32 MFMA/barrier-pair) — gemm_out recipe.

// ---------------- kernel A: fp32 -> bf16 conversion ----------------
__global__ __launch_bounds__(256) void convert_all(
    const float* __restrict__ x, const float* __restrict__ wq,
    const float* __restrict__ wk, const float* __restrict__ wv,
    const float* __restrict__ wo, ushort* __restrict__ dst)
{
  size_t i = ((size_t)blockIdx.x * 256 + threadIdx.x) * 4;
  const float* src; size_t off;
  if (i < (size_t)2097152) { src = x; off = i; }
  else {
    size_t j = i - 2097152;
    unsigned wsel = (unsigned)(j >> 19);
    off = j & 524287;
    src = wsel == 0 ? wq : wsel == 1 ? wk : wsel == 2 ? wv : wo;
  }
  float4 v = *(const float4*)(src + off);
  ushort4 o;
  o.x = f2bf(v.x); o.y = f2bf(v.y); o.z = f2bf(v.z); o.w = f2bf(v.w);
  *(ushort4*)(dst + i) = o;
}

// ---------------- QKV GEMM (NT), BK=64 ----------------
// A[8192,256] x {Wq|Wk|Wv}[2048,256]^T; grid (48,64): x = 16 n-tiles x 3 proj.
template<int BM, int BN>
__global__ __launch_bounds__(256, 2) void gemm_qkv(
    const ushort* __restrict__ A,
    const ushort* __restrict__ W0, const ushort* __restrict__ W1, const ushort* __restrict__ W2,
    int K,
    const float* __restrict__ b0, const float* __restrict__ b1, const float* __restrict__ b2,
    ushort* __restrict__ Qo, ushort* __restrict__ Ko, ushort* __restrict__ Vo)
{
  constexpr int WM = BM / 2, WN = BN / 2, MF = WM / 16, NF = WN / 16;
  const int n0 = blockIdx.x * BN, m0 = blockIdx.y * BM;
  const int tid = threadIdx.x, lane = tid & 63;
  const int wm = (tid >> 7) & 1, wn = (tid >> 6) & 1;
  const int g = lane >> 4, r15 = lane & 15;

  __shared__ ushort As[BM * 72];
  __shared__ ushort Bs[BN * 72];

  const int p = n0 >> 11;
  const ushort* Bt = (p == 0 ? W0 : p == 1 ? W1 : W2) + (size_t)(n0 & 2047) * K;

  f32x4 acc[MF][NF];
#pragma unroll
  for (int m = 0; m < MF; m++)
#pragma unroll
    for (int n = 0; n < NF; n++) acc[m][n] = (f32x4){0.f, 0.f, 0.f, 0.f};

  for (int k0 = 0; k0 < K; k0 += 64) {
#pragma unroll
    for (int i = 0; i < 4; i++) {
      int ci = tid * 4 + i; int r = ci >> 3, c = ci & 7;
      *(uint4*)&As[r * 72 + c * 8] = *(const uint4*)&A[(size_t)(m0 + r) * K + k0 + c * 8];
      *(uint4*)&Bs[r * 72 + c * 8] = *(const uint4*)&Bt[(size_t)r * K + k0 + c * 8];
    }
    __syncthreads();
    bf16x8 af[MF][2], bfr[NF][2];
#pragma unroll
    for (int m = 0; m < MF; m++)
#pragma unroll
      for (int k2 = 0; k2 < 2; ++k2)
        af[m][k2] = *(const bf16x8*)&As[(wm * WM + m * 16 + r15) * 72 + k2 * 32 + g * 8];
#pragma unroll
    for (int n = 0; n < NF; n++)
#pragma unroll
      for (int k2 = 0; k2 < 2; ++k2)
        bfr[n][k2] = *(const bf16x8*)&Bs[(wn * WN + n * 16 + r15) * 72 + k2 * 32 + g * 8];
#pragma unroll
    for (int k2 = 0; k2 < 2; ++k2)
#pragma unroll
      for (int m = 0; m < MF; m++)
#pragma unroll
        for (int n = 0; n < NF; n++) acc[m][n] = mfma16(af[m][k2], bfr[n][k2], acc[m][n]);
    __syncthreads();
  }

  const float* bias = (p == 0 ? b0 : p == 1 ? b1 : b2);
  const float scl = (p == 0 ? 0.0625f : 1.0f);
#pragma unroll
  for (int m = 0; m < MF; m++)
#pragma unroll
    for (int n = 0; n < NF; n++)
#pragma unroll
      for (int r = 0; r < 4; r++) {
        int row = m0 + wm * WM + m * 16 + g * 4 + r;
        int col = n0 + wn * WN + n * 16 + r15;
        int ce = col & 2047;
        float v = (acc[m][n][r] + bias[ce]) * scl;
        int b = row >> 11, s = row & 2047, h = ce >> 8, e = ce & 255;
        int bh = b * 8 + h;
        if (p == 0) {
          Qo[((size_t)(bh * 2048 + s) << 8) + e] = f2bf(v);
        } else if (p == 1) {
          int ee = ((((e >> 3) ^ (s & 7)) & 31) << 3) | (e & 7); // T2 pre-swizzle
          Ko[((size_t)(bh * 2048 + s) << 8) + ee] = f2bf(v);
        } else {
          // tiled V': [bh][s>>5][e][s&31]
          Vo[(((size_t)bh * 64 + (s >> 5)) << 13) + e * 32 + (s & 31)] = f2bf(v);
        }
      }
}

// ---------------- out GEMM: [8192,2048] x Wo[256,2048]^T + bo -> fp32 [8192,256] ----------------
__global__ __launch_bounds__(256, 2) void gemm_out(
    const ushort* __restrict__ A, const ushort* __restrict__ Bw,
    const float* __restrict__ bias, float* __restrict__ out)
{
  const int n0 = blockIdx.x * 64, m0 = blockIdx.y * 64;
  const int tid = threadIdx.x, lane = tid & 63;
  const int wm = (tid >> 7) & 1, wn = (tid >> 6) & 1;
  const int g = lane >> 4, r15 = lane & 15;

  __shared__ ushort As[64 * 72];
  __shared__ ushort Bs[64 * 72];

  f32x4 acc[2][2];
#pragma unroll
  for (int m = 0; m < 2; m++)
#pragma unroll
    for (int n = 0; n < 2; n++) acc[m][n] = (f32x4){0.f, 0.f, 0.f, 0.f};

  for (int k0 = 0; k0 < 2048; k0 += 64) {
#pragma unroll
    for (int i = 0; i < 2; ++i) {
      int ci = tid * 2 + i, r = ci >> 3, c = ci & 7;
      *(uint4*)&As[r * 72 + c * 8] = *(const uint4*)&A[(size_t)(m0 + r) * 2048 + k0 + c * 8];
      *(uint4*)&Bs[r * 72 + c * 8] = *(const uint4*)&Bw[(size_t)(n0 + r) * 2048 + k0 + c * 8];
    }
    __syncthreads();
    bf16x8 af[2][2], bfr[2][2];
#pragma unroll
    for (int m = 0; m < 2; ++m)
#pragma unroll
      for (int k2 = 0; k2 < 2; ++k2)
        af[m][k2] = *(const bf16x8*)&As[(wm * 32 + m * 16 + r15) * 72 + k2 * 32 + g * 8];
#pragma unroll
    for (int n = 0; n < 2; ++n)
#pragma unroll
      for (int k2 = 0; k2 < 2; ++k2)
        bfr[n][k2] = *(const bf16x8*)&Bs[(wn * 32 + n * 16 + r15) * 72 + k2 * 32 + g * 8];
#pragma unroll
    for (int k2 = 0; k2 < 2; ++k2)
#pragma unroll
      for (int m = 0; m < 2; ++m)
#pragma unroll
        for (int n = 0; n < 2; ++n)
          acc[m][n] = mfma16(af[m][k2], bfr[n][k2], acc[m][n]);
    __syncthreads();
  }

#pragma unroll
  for (int m = 0; m < 2; m++)
#pragma unroll
    for (int n = 0; n < 2; n++)
#pragma unroll
      for (int r = 0; r < 4; r++) {
        int row = m0 + wm * 32 + m * 16 + g * 4 + r;
        int col = n0 + wn * 32 + n * 16 + r15;
        out[(size_t)row * 256 + col] = acc[m][n][r] + bias[col];
      }
}

// ---------------- attention phase 0: s-tile 128, t-halved, single-buffer (r15, proven) ----------------
__global__ __launch_bounds__(256, 4) void attn_p0(
    const ushort* __restrict__ Qb, const ushort* __restrict__ Kb,
    float* __restrict__ lpart)
{
  const int bid = blockIdx.x;
  const int swz = (bid & 7) * 128 + (bid >> 3);   // bijective: 1024 % 8 == 0
  const int bh = swz >> 5, stile = (swz >> 1) & 15, half = swz & 1;
  const int s0 = stile * 128;
  const int tid = threadIdx.x, lane = tid & 63, w = tid >> 6;
  const int g = lane >> 4, r15 = lane & 15;

  __shared__ __align__(16) ushort Ks[8192];   // [32 t][256 k] single buffer, swizzled

  uint4 qr[2][8];
#pragma unroll
  for (int h = 0; h < 2; ++h) {
    const ushort* qrow = &Qb[((size_t)bh * 2048 + s0 + w * 32 + h * 16 + r15) * 256 + g * 8];
#pragma unroll
    for (int kk = 0; kk < 8; kk++) qr[h][kk] = *(const uint4*)&qrow[kk * 32];
  }
  // pin q: opaque to rematerialization (per-32-bit-component ties — r14 lesson)
#pragma unroll
  for (int h = 0; h < 2; ++h)
#pragma unroll
    for (int kk = 0; kk < 8; kk++)
      asm volatile("" : "+v"(qr[h][kk].x), "+v"(qr[h][kk].y),
                        "+v"(qr[h][kk].z), "+v"(qr[h][kk].w));

  const ushort* Ktile = Kb + ((size_t)bh << 19);
  const int it0 = half * 32, it1 = it0 + 32;

  for (int it = it0; it < it1; ++it) {
    uint4 st[4];
#pragma unroll
    for (int i = 0; i < 4; ++i)
      st[i] = *(const uint4*)&Ktile[(size_t)it * 8192 + (i * 256 + tid) * 8];
#pragma unroll
    for (int i = 0; i < 4; ++i)
      *(uint4*)&Ks[(i * 256 + tid) * 8] = st[i];
    __syncthreads();   // Ks visible

#pragma unroll
    for (int n = 0; n < 2; ++n) {
      f32x4 g0 = (f32x4){0.f, 0.f, 0.f, 0.f};
      f32x4 g1 = (f32x4){0.f, 0.f, 0.f, 0.f};
#pragma unroll
      for (int kk = 0; kk < 8; ++kk) {
        bf16x8 kb = *(const bf16x8*)&Ks[(n * 16 + r15) * 256 + (((kk * 4 + g) ^ (r15 & 7)) << 3)];
        g0 = mfma16(*(const bf16x8*)&qr[0][kk], kb, g0);
        g1 = mfma16(*(const bf16x8*)&qr[1][kk], kb, g1);
      }
      float sn = __expf(g0[0]) + __expf(g0[1]) + __expf(g0[2]) + __expf(g0[3])
               + __expf(g1[0]) + __expf(g1[1]) + __expf(g1[2]) + __expf(g1[3]);
      sn += __shfl_xor(sn, 16);
      sn += __shfl_xor(sn, 32);
      if (g == 0)
        lpart[((size_t)((stile * 4 + w) * 32 + bh) << 11) + it * 32 + n * 16 + r15] = sn;
    }
    __syncthreads();   // reads done before next iter's writes
  }
}

// ---------------- attention phase 1: s-tile 128 + one-barrier pipeline (r10 QK^T, proven 143us) ----------------
__global__ __launch_bounds__(256, 2) void attn_p1(
    const ushort* __restrict__ Qb, const ushort* __restrict__ Kb,
    const ushort* __restrict__ Vt, ushort* __restrict__ Zb)
{
  const int bid = blockIdx.x;
  const int swz = (bid & 7) * 64 + (bid >> 3);   // bijective: 512 % 8 == 0
  const int bh = swz >> 4, stile = swz & 15;
  const int s0 = stile * 128;
  const int tid = threadIdx.x, lane = tid & 63, w = tid >> 6;
  const int g = lane >> 4, r15 = lane & 15;

  __shared__ __align__(16) ushort Ks[2][8192];   // dbuf K tile [32 t][256 k], swizzled
  __shared__ __align__(16) ushort Ps[2][5120];   // dbuf [128 s][40]

  bf16x8 q[2][8];
#pragma unroll
  for (int h = 0; h < 2; ++h) {
    const ushort* qrow = &Qb[((size_t)bh * 2048 + s0 + w * 32 + h * 16 + r15) * 256 + g * 8];
#pragma unroll
    for (int kk = 0; kk < 8; kk++) q[h][kk] = *(const bf16x8*)&qrow[kk * 32];
  }

  const ushort* Ktile = Kb + ((size_t)bh << 19);
  const ushort* Vtile = Vt + ((size_t)bh << 19);

  f32x4 acc[8][4];
#pragma unroll
  for (int m = 0; m < 8; m++)
#pragma unroll
    for (int n = 0; n < 4; n++) acc[m][n] = (f32x4){0.f, 0.f, 0.f, 0.f};

  // prologue: stage K(0) into Ks[0]
  {
    uint4 p0[4];
#pragma unroll
    for (int i = 0; i < 4; ++i)
      p0[i] = *(const uint4*)&Ktile[(size_t)(i * 256 + tid) * 8];
#pragma unroll
    for (int i = 0; i < 4; ++i)
      *(uint4*)&Ks[0][(i * 256 + tid) * 8] = p0[i];
  }
  __syncthreads();

  for (int it = 0; it < 64; ++it) {
    const int cur = it & 1;
    // ---- top clump: V(it) frags + K(it+1) stage loads ----
    bf16x8 vb[4];
#pragma unroll
    for (int n = 0; n < 4; ++n)
      vb[n] = *(const bf16x8*)&Vtile[(size_t)it * 8192 + (w * 64 + n * 16 + r15) * 32 + g * 8];
    uint4 st[4];
    if (it < 63) {
#pragma unroll
      for (int i = 0; i < 4; ++i)
        st[i] = *(const uint4*)&Ktile[(size_t)(it + 1) * 8192 + (i * 256 + tid) * 8];
    }

    // ---- QK^T: this wave's 32 s-rows x 32 t from Ks[cur] (r10 structure) ----
#pragma unroll
    for (int h = 0; h < 2; ++h) {
      f32x4 gg[2];
      gg[0] = (f32x4){0.f, 0.f, 0.f, 0.f};
      gg[1] = (f32x4){0.f, 0.f, 0.f, 0.f};
#pragma unroll
      for (int n = 0; n < 2; ++n)
#pragma unroll
        for (int kk = 0; kk < 8; ++kk) {
          bf16x8 kb = *(const bf16x8*)&Ks[cur][(n * 16 + r15) * 256 + (((kk * 4 + g) ^ (r15 & 7)) << 3)];
          gg[n] = mfma16(q[h][kk], kb, gg[n]);
        }
#pragma unroll
      for (int n = 0; n < 2; ++n)
#pragma unroll
        for (int rr = 0; rr < 4; ++rr)
          Ps[cur][(w * 32 + h * 16 + g * 4 + rr) * 40 + n * 16 + r15] = f2bf(__expf(gg[n][rr]));
    }

    // ---- ds_write K(it+1): vmcnt wait covered by QK^T+exp above ----
    if (it < 63) {
#pragma unroll
      for (int i = 0; i < 4; ++i)
        *(uint4*)&Ks[cur ^ 1][(i * 256 + tid) * 8] = st[i];
    }

    __syncthreads();   // ONE barrier: Ps[cur]+Ks[cur^1] visible; prev reads done

    // ---- PV: all 128 s x this wave's 64 e ----
#pragma unroll
    for (int mh = 0; mh < 2; ++mh) {
      bf16x8 pa[4];
#pragma unroll
      for (int m = 0; m < 4; ++m)
        pa[m] = *(const bf16x8*)&Ps[cur][((mh * 4 + m) * 16 + r15) * 40 + g * 8];
#pragma unroll
      for (int n = 0; n < 4; ++n)
#pragma unroll
        for (int m = 0; m < 4; ++m)
          acc[mh * 4 + m][n] = mfma16(pa[m], vb[n], acc[mh * 4 + m][n]);
    }
  }

  const int b = bh >> 3, h = bh & 7;
#pragma unroll
  for (int m = 0; m < 8; m++)
#pragma unroll
    for (int n = 0; n < 4; n++)
#pragma unroll
      for (int rr = 0; rr < 4; rr++) {
        int sl = m * 16 + g * 4 + rr;
        int el = w * 64 + n * 16 + r15;
        Zb[((size_t)(b * 2048 + s0 + sl)) * 2048 + h * 256 + el] = f2bf(acc[m][n][rr]);
      }
}

// ---------------- V' in-place scale by 1/l_t (64 partials) ----------------
__global__ __launch_bounds__(256) void vscale(
    ushort* __restrict__ Vt, const float* __restrict__ lp)
{
  const int tt = blockIdx.x, bh = blockIdx.y, tid = threadIdx.x;
  const int t = tid & 31, pg = tid >> 5;
  __shared__ float red[256];
  __shared__ float cinv[32];
  float s = 0.f;
  for (int p = pg * 8; p < pg * 8 + 8; ++p)
    s += lp[(((size_t)p * 32 + bh) << 11) + tt * 32 + t];
  red[tid] = s;
  __syncthreads();
  if (tid < 32) {
    float tot = 0.f;
#pragma unroll
    for (int i = 0; i < 8; ++i) tot += red[tid + i * 32];
    cinv[tid] = 1.0f / tot;
  }
  __syncthreads();
  size_t base = (((size_t)bh * 64 + tt) << 13) + (size_t)tid * 32;
  ushort buf[32];
#pragma unroll
  for (int i = 0; i < 4; ++i) *(uint4*)&buf[i * 8] = *(const uint4*)&Vt[base + i * 8];
#pragma unroll
  for (int j = 0; j < 32; ++j) buf[j] = f2bf(bf2f(buf[j]) * cinv[j]);
#pragma unroll
  for (int i = 0; i < 4; ++i) *(uint4*)&Vt[base + i * 8] = *(const uint4*)&buf[i * 8];
}

// ---------------- launch ----------------
extern "C" void kernel_launch(void* const* d_in, const int* in_sizes, int n_in,
                              void* d_out, int out_size, void* d_ws, size_t ws_size,
                              hipStream_t stream) {
  const float* x  = (const float*)d_in[0];
  const float* Wq = (const float*)d_in[1];
  const float* bq = (const float*)d_in[2];
  const float* Wk = (const float*)d_in[3];
  const float* bk = (const float*)d_in[4];
  const float* Wv = (const float*)d_in[5];
  const float* bv = (const float*)d_in[6];
  const float* Wo = (const float*)d_in[7];
  const float* bo = (const float*)d_in[8];

  if (ws_size < (size_t)176160768) return; // need 168 MB scratch

  char* ws = (char*)d_ws;
  ushort* bfb = (ushort*)ws;                       // bf16 conversions (8 MB)
  ushort* xb  = bfb;
  ushort* wqb = bfb + 2097152;
  ushort* wkb = bfb + 2621440;
  ushort* wvb = bfb + 3145728;
  ushort* wob = bfb + 3670016;
  ushort* Qb = (ushort*)(ws + 8388608);            // [32,2048,256] (Q pre-scaled 1/16)
  ushort* Kb = (ushort*)(ws + 41943040);           // [32,2048,256] T2-swizzled
  ushort* Vt = (ushort*)(ws + 75497472);           // [32,64,256,32] tiled V'
  ushort* Zb = (ushort*)(ws + 109051904);          // [8192,2048]
  float*  lp = (float*)(ws + 142606336);           // [64,32,2048] fp32 partial colsums
  float* out = (float*)d_out;

  convert_all<<<4096, 256, 0, stream>>>(x, Wq, Wk, Wv, Wo, bfb);
  gemm_qkv<128, 128><<<dim3(48, 64), 256, 0, stream>>>(
      xb, wqb, wkb, wvb, 256, bq, bk, bv, Qb, Kb, Vt);
  attn_p0<<<1024, 256, 0, stream>>>(Qb, Kb, lp);
  vscale<<<dim3(64, 32), 256, 0, stream>>>(Vt, lp);
  attn_p1<<<512, 256, 0, stream>>>(Qb, Kb, Vt, Zb);
  gemm_out<<<dim3(4, 128), 256, 0, stream>>>(Zb, wob, bo, out);
}